// Round 1
// baseline (40707.663 us; speedup 1.0000x reference)
//
#include <hip/hip_runtime.h>
#include <math.h>

#define F4(p) (*reinterpret_cast<const float4*>(p))

constexpr int D    = 512;
constexpr int H    = 8;
constexpr int HD   = 64;
constexpr int NL   = 6;
constexpr int NB   = 64;     // batch
constexpr int M    = 20;     // context length
constexpr int T    = 30;     // max_tokens (input constant)
constexpr int SMAX = 49;     // 20 + 29 positions
constexpr int NR   = NB * M; // 1280 prefill rows
constexpr float EPS   = 1e-5f;
constexpr float SCALE = 0.125f; // 1/sqrt(64)

#define GM_PLAIN 0
#define GM_QKV   1

__device__ __forceinline__ float wave_sum(float v){
  #pragma unroll
  for (int o = 32; o > 0; o >>= 1) v += __shfl_down(v, o, 64);
  return v;
}

// 256-thread block sum; red must hold >=4 floats
__device__ __forceinline__ float block_sum(float v, float* red){
  v = wave_sum(v);
  int wid = threadIdx.x >> 6, lane = threadIdx.x & 63;
  if (lane == 0) red[wid] = v;
  __syncthreads();
  if (threadIdx.x == 0) red[0] = red[0] + red[1] + red[2] + red[3];
  __syncthreads();
  float tot = red[0];
  __syncthreads();
  return tot;
}

__device__ __forceinline__ float gelu_f(float x){
  return 0.5f * x * (1.f + erff(x * 0.70710678118654752f));
}

// dot of K-length LDS vector x with global row w; 8 lanes (j=0..7) cooperate.
// Returns full sum on all 8 lanes of the group.
template<int K>
__device__ __forceinline__ float dot8(const float* __restrict__ w, const float* x, int j){
  float a0 = 0.f, a1 = 0.f;
  #pragma unroll
  for (int r = 0; r < K/64; r++){
    int d = j*4 + r*64;
    float4 w0 = F4(w + d);        float4 w1 = F4(w + d + 32);
    float4 x0 = F4(x + d);        float4 x1 = F4(x + d + 32);
    a0 += w0.x*x0.x + w0.y*x0.y + w0.z*x0.z + w0.w*x0.w;
    a1 += w1.x*x1.x + w1.y*x1.y + w1.z*x1.z + w1.w*x1.w;
  }
  float a = a0 + a1;
  a += __shfl_xor(a, 4, 8);
  a += __shfl_xor(a, 2, 8);
  a += __shfl_xor(a, 1, 8);
  return a;
}

// -------------------- prefill kernels --------------------

__global__ __launch_bounds__(256) void k_embed(const float* __restrict__ ctx,
    const float* __restrict__ pos, float* __restrict__ X0){
  int r = blockIdx.x, t = threadIdx.x, s = r % M;
  X0[(size_t)r*D + t]       = ctx[(size_t)r*D + t]       + pos[(size_t)s*D + t];
  X0[(size_t)r*D + t + 256] = ctx[(size_t)r*D + t + 256] + pos[(size_t)s*D + t + 256];
}

__global__ __launch_bounds__(256) void k_ln(const float* __restrict__ x, float* __restrict__ y,
    const float* __restrict__ g, const float* __restrict__ bb){
  __shared__ float red[4];
  int r = blockIdx.x, t = threadIdx.x;
  const float* xr = x + (size_t)r*D;
  float v0 = xr[t], v1 = xr[t+256];
  float mean = block_sum(v0+v1, red) * (1.f/D);
  float d0 = v0-mean, d1 = v1-mean;
  float var = block_sum(d0*d0 + d1*d1, red) * (1.f/D);
  float rs = rsqrtf(var + EPS);
  float* yr = y + (size_t)r*D;
  yr[t]     = d0*rs*g[t]     + bb[t];
  yr[t+256] = d1*rs*g[t+256] + bb[t+256];
}

// C(M,N) = A(M,K) @ W(N,K)^T + bias ; optional residual, gelu; QKV scatter mode.
// grid (M/64, N/64), 256 threads, 4x4 microtile.
__global__ __launch_bounds__(256) void k_gemm(
    const float* __restrict__ A, const float* __restrict__ W,
    const float* __restrict__ bias, const float* __restrict__ res,
    float* __restrict__ C, int K, int ldc, int gelu_flag,
    float* __restrict__ q0, float* __restrict__ kc, float* __restrict__ vc, int mode){
  __shared__ __align__(16) float As[32][64];
  __shared__ __align__(16) float Ws[32][64];
  int m0 = blockIdx.x*64, n0 = blockIdx.y*64;
  int t = threadIdx.x, tx = t & 15, ty = t >> 4;
  float acc[4][4] = {};
  for (int k0 = 0; k0 < K; k0 += 32){
    #pragma unroll
    for (int i = 0; i < 2; i++){
      int idx = t + i*256;
      int m = idx & 63, k4 = idx >> 6;
      float4 a = F4(A + (size_t)(m0+m)*K + k0 + k4*4);
      As[k4*4+0][m]=a.x; As[k4*4+1][m]=a.y; As[k4*4+2][m]=a.z; As[k4*4+3][m]=a.w;
      float4 w = F4(W + (size_t)(n0+m)*K + k0 + k4*4);
      Ws[k4*4+0][m]=w.x; Ws[k4*4+1][m]=w.y; Ws[k4*4+2][m]=w.z; Ws[k4*4+3][m]=w.w;
    }
    __syncthreads();
    #pragma unroll
    for (int k = 0; k < 32; k++){
      float4 a = *reinterpret_cast<float4*>(&As[k][ty*4]);
      float4 w = *reinterpret_cast<float4*>(&Ws[k][tx*4]);
      float av[4] = {a.x,a.y,a.z,a.w};
      float wv[4] = {w.x,w.y,w.z,w.w};
      #pragma unroll
      for (int i = 0; i < 4; i++)
        #pragma unroll
        for (int jj = 0; jj < 4; jj++) acc[i][jj] += av[i]*wv[jj];
    }
    __syncthreads();
  }
  #pragma unroll
  for (int i = 0; i < 4; i++){
    int row = m0 + ty*4 + i;
    #pragma unroll
    for (int jj = 0; jj < 4; jj++){
      int col = n0 + tx*4 + jj;
      float v = acc[i][jj] + bias[col];
      if (res) v += res[(size_t)row*ldc + col];
      if (gelu_flag) v = gelu_f(v);
      if (mode == GM_PLAIN){
        C[(size_t)row*ldc + col] = v;
      } else {
        if (col < D) q0[(size_t)row*D + col] = v;
        else {
          int b = row / M, s = row % M;
          float* dst = (col < 2*D) ? kc : vc;
          dst[((size_t)b*SMAX + s)*D + (col & (D-1))] = v;
        }
      }
    }
  }
}

// prefill causal self-attn: one block per (b,h)
__global__ __launch_bounds__(256) void k_sattn_pre(const float* __restrict__ Q0,
    const float* __restrict__ kc, const float* __restrict__ vc, float* __restrict__ AT0){
  int b = blockIdx.x >> 3, h = blockIdx.x & 7, t = threadIdx.x;
  __shared__ __align__(16) float q[M][HD], kk[M][HD], vv[M][HD];
  __shared__ float sc[M][M];
  for (int idx = t; idx < M*HD; idx += 256){
    int s = idx >> 6, e = idx & 63;
    q[s][e]  = Q0[((size_t)b*M + s)*D + h*HD + e];
    kk[s][e] = kc[((size_t)b*SMAX + s)*D + h*HD + e];
    vv[s][e] = vc[((size_t)b*SMAX + s)*D + h*HD + e];
  }
  __syncthreads();
  for (int idx = t; idx < M*M; idx += 256){
    int qs = idx / M, ks = idx % M;
    if (ks <= qs){
      float s = 0.f;
      #pragma unroll
      for (int e = 0; e < HD; e++) s += q[qs][e]*kk[ks][e];
      sc[qs][ks] = s * SCALE;
    }
  }
  __syncthreads();
  if (t < M){
    float mx = -1e30f;
    for (int ks = 0; ks <= t; ks++) mx = fmaxf(mx, sc[t][ks]);
    float sum = 0.f;
    for (int ks = 0; ks <= t; ks++){ float e = expf(sc[t][ks]-mx); sc[t][ks] = e; sum += e; }
    float inv = 1.f/sum;
    for (int ks = 0; ks <= t; ks++) sc[t][ks] *= inv;
  }
  __syncthreads();
  for (int idx = t; idx < M*HD; idx += 256){
    int qs = idx >> 6, e = idx & 63;
    float o = 0.f;
    for (int ks = 0; ks <= qs; ks++) o += sc[qs][ks]*vv[ks][e];
    AT0[((size_t)b*M + qs)*D + h*HD + e] = o;
  }
}

// prefill cross-attn (keys = cached context K/V, no mask)
__global__ __launch_bounds__(256) void k_cattn_pre(const float* __restrict__ Q0,
    const float* __restrict__ ckv, float* __restrict__ AT0){
  int b = blockIdx.x >> 3, h = blockIdx.x & 7, t = threadIdx.x;
  __shared__ __align__(16) float q[M][HD], kk[M][HD], vv[M][HD];
  __shared__ float sc[M][M];
  for (int idx = t; idx < M*HD; idx += 256){
    int s = idx >> 6, e = idx & 63;
    q[s][e]  = Q0[((size_t)b*M + s)*D + h*HD + e];
    kk[s][e] = ckv[((size_t)b*M + s)*1024 + h*HD + e];
    vv[s][e] = ckv[((size_t)b*M + s)*1024 + D + h*HD + e];
  }
  __syncthreads();
  for (int idx = t; idx < M*M; idx += 256){
    int qs = idx / M, ks = idx % M;
    float s = 0.f;
    #pragma unroll
    for (int e = 0; e < HD; e++) s += q[qs][e]*kk[ks][e];
    sc[qs][ks] = s * SCALE;
  }
  __syncthreads();
  if (t < M){
    float mx = -1e30f;
    for (int ks = 0; ks < M; ks++) mx = fmaxf(mx, sc[t][ks]);
    float sum = 0.f;
    for (int ks = 0; ks < M; ks++){ float e = expf(sc[t][ks]-mx); sc[t][ks] = e; sum += e; }
    float inv = 1.f/sum;
    for (int ks = 0; ks < M; ks++) sc[t][ks] *= inv;
  }
  __syncthreads();
  for (int idx = t; idx < M*HD; idx += 256){
    int qs = idx >> 6, e = idx & 63;
    float o = 0.f;
    for (int ks = 0; ks < M; ks++) o += sc[qs][ks]*vv[ks][e];
    AT0[((size_t)b*M + qs)*D + h*HD + e] = o;
  }
}

__global__ __launch_bounds__(256) void k_copy_last(const float* __restrict__ X0,
    float* __restrict__ xb){
  int b = blockIdx.x, t = threadIdx.x;
  xb[(size_t)b*D + t]       = X0[((size_t)b*M + M-1)*D + t];
  xb[(size_t)b*D + t + 256] = X0[((size_t)b*M + M-1)*D + t + 256];
}

// logits for step tstep from xb, then xb <- xb + pos_enc[pnext]
__global__ __launch_bounds__(256) void k_final(float* __restrict__ xb,
    const float* __restrict__ pos, const float* __restrict__ ow, const float* __restrict__ ob,
    float* __restrict__ out, int tstep, int pnext){
  int b = blockIdx.x, t = threadIdx.x;
  __shared__ __align__(16) float x[D];
  x[t] = xb[(size_t)b*D + t]; x[t+256] = xb[(size_t)b*D + t + 256];
  __syncthreads();
  int c = t >> 5, lane = t & 31;
  float a = 0.f;
  for (int d = lane*4; d < D; d += 128){
    float4 wv = F4(ow + (size_t)c*D + d);
    a += wv.x*x[d] + wv.y*x[d+1] + wv.z*x[d+2] + wv.w*x[d+3];
  }
  a += __shfl_xor(a, 16, 32); a += __shfl_xor(a, 8, 32);
  a += __shfl_xor(a, 4, 32);  a += __shfl_xor(a, 2, 32); a += __shfl_xor(a, 1, 32);
  if (lane == 0) out[((size_t)b*T + tstep)*8 + c] = a + ob[c];
  xb[(size_t)b*D + t]       = x[t]     + pos[(size_t)pnext*D + t];
  xb[(size_t)b*D + t + 256] = x[t+256] + pos[(size_t)pnext*D + t + 256];
}

// -------------------- decode kernels --------------------

// LN1 + QKV projection for the single new position; appends K/V to cache.
__global__ __launch_bounds__(256) void k_dqkv(const float* __restrict__ xb,
    const float* __restrict__ w, const float* __restrict__ bias,
    const float* __restrict__ g, const float* __restrict__ bb,
    float* __restrict__ qb, float* __restrict__ kc, float* __restrict__ vc, int p){
  __shared__ __align__(16) float xn[D];
  __shared__ float red[4];
  int blk = blockIdx.x, b = blk/6, ch = blk%6, t = threadIdx.x, j = t & 7;
  float v0 = xb[(size_t)b*D + t], v1 = xb[(size_t)b*D + t + 256];
  float mean = block_sum(v0+v1, red) * (1.f/D);
  float d0 = v0-mean, d1 = v1-mean;
  float var = block_sum(d0*d0 + d1*d1, red) * (1.f/D);
  float rs = rsqrtf(var + EPS);
  xn[t]     = d0*rs*g[t]     + bb[t];
  xn[t+256] = d1*rs*g[t+256] + bb[t+256];
  __syncthreads();
  #pragma unroll
  for (int pass = 0; pass < 8; pass++){
    int o = ch*256 + pass*32 + (t >> 3);
    float r = dot8<512>(w + (size_t)o*D, xn, j);
    if (j == 0){
      r += bias[o];
      if (o < D)        qb[(size_t)b*D + o] = r;
      else if (o < 2*D) kc[((size_t)b*SMAX + p)*D + o - D]   = r;
      else              vc[((size_t)b*SMAX + p)*D + o - 2*D] = r;
    }
  }
}

// self-attn + out-proj + res + LN2 + cross-q + cross-attn + cross-out + res + LN3
// One block per batch row.
__global__ __launch_bounds__(256) void k_dmid(float* __restrict__ xb,
    const float* __restrict__ qb,
    const float* __restrict__ kc, const float* __restrict__ vc, const float* __restrict__ ckv,
    const float* __restrict__ sow, const float* __restrict__ sob,
    const float* __restrict__ cqw, const float* __restrict__ cqb,
    const float* __restrict__ cow, const float* __restrict__ cob,
    const float* __restrict__ g2, const float* __restrict__ b2,
    const float* __restrict__ g3, const float* __restrict__ b3,
    float* __restrict__ xnb, int p){
  int b = blockIdx.x, t = threadIdx.x, j = t & 7, S = p + 1;
  __shared__ __align__(16) float q[D], at[D], x1[D], xn[D];
  __shared__ float sc[H][SMAX+3];
  __shared__ float red[4];
  q[t] = qb[(size_t)b*D + t]; q[t+256] = qb[(size_t)b*D + t + 256];
  __syncthreads();
  const float* kb = kc + (size_t)b*SMAX*D;
  const float* vb = vc + (size_t)b*SMAX*D;
  for (int idx = t; idx < H*S; idx += 256){
    int h = idx / S, ks = idx % S;
    const float* kr = kb + (size_t)ks*D + h*HD;
    float s = 0.f;
    #pragma unroll
    for (int e = 0; e < HD; e += 4){
      float4 kv = F4(kr + e);
      s += kv.x*q[h*HD+e] + kv.y*q[h*HD+e+1] + kv.z*q[h*HD+e+2] + kv.w*q[h*HD+e+3];
    }
    sc[h][ks] = s * SCALE;
  }
  __syncthreads();
  if (t < H){
    float mx = -1e30f;
    for (int ks = 0; ks < S; ks++) mx = fmaxf(mx, sc[t][ks]);
    float sum = 0.f;
    for (int ks = 0; ks < S; ks++){ float e = expf(sc[t][ks]-mx); sc[t][ks] = e; sum += e; }
    float inv = 1.f/sum;
    for (int ks = 0; ks < S; ks++) sc[t][ks] *= inv;
  }
  __syncthreads();
  for (int idx = t; idx < D; idx += 256){
    int h = idx >> 6, e = idx & 63;
    float o = 0.f;
    for (int ks = 0; ks < S; ks++) o += sc[h][ks]*vb[(size_t)ks*D + h*HD + e];
    at[idx] = o;
  }
  __syncthreads();
  // out-proj + residual
  #pragma unroll
  for (int pass = 0; pass < 16; pass++){
    int o = pass*32 + (t >> 3);
    float r = dot8<512>(sow + (size_t)o*D, at, j);
    if (j == 0) x1[o] = r + sob[o] + xb[(size_t)b*D + o];
  }
  __syncthreads();
  { // LN2 -> xn
    float v0 = x1[t], v1 = x1[t+256];
    float mean = block_sum(v0+v1, red) * (1.f/D);
    float d0 = v0-mean, d1 = v1-mean;
    float var = block_sum(d0*d0 + d1*d1, red) * (1.f/D);
    float rs = rsqrtf(var + EPS);
    xn[t]     = d0*rs*g2[t]     + b2[t];
    xn[t+256] = d1*rs*g2[t+256] + b2[t+256];
  }
  __syncthreads();
  // cross-q (into q)
  #pragma unroll
  for (int pass = 0; pass < 16; pass++){
    int o = pass*32 + (t >> 3);
    float r = dot8<512>(cqw + (size_t)o*D, xn, j);
    if (j == 0) q[o] = r + cqb[o];
  }
  __syncthreads();
  const float* cb_ = ckv + (size_t)b*M*1024;
  for (int idx = t; idx < H*M; idx += 256){
    int h = idx / M, ks = idx % M;
    const float* kr = cb_ + (size_t)ks*1024 + h*HD;
    float s = 0.f;
    #pragma unroll
    for (int e = 0; e < HD; e += 4){
      float4 kv = F4(kr + e);
      s += kv.x*q[h*HD+e] + kv.y*q[h*HD+e+1] + kv.z*q[h*HD+e+2] + kv.w*q[h*HD+e+3];
    }
    sc[h][ks] = s * SCALE;
  }
  __syncthreads();
  if (t < H){
    float mx = -1e30f;
    for (int ks = 0; ks < M; ks++) mx = fmaxf(mx, sc[t][ks]);
    float sum = 0.f;
    for (int ks = 0; ks < M; ks++){ float e = expf(sc[t][ks]-mx); sc[t][ks] = e; sum += e; }
    float inv = 1.f/sum;
    for (int ks = 0; ks < M; ks++) sc[t][ks] *= inv;
  }
  __syncthreads();
  for (int idx = t; idx < D; idx += 256){
    int h = idx >> 6, e = idx & 63;
    float o = 0.f;
    for (int ks = 0; ks < M; ks++) o += sc[h][ks]*cb_[(size_t)ks*1024 + D + h*HD + e];
    at[idx] = o;
  }
  __syncthreads();
  // cross out-proj + residual -> x1, write xb
  #pragma unroll
  for (int pass = 0; pass < 16; pass++){
    int o = pass*32 + (t >> 3);
    float r = dot8<512>(cow + (size_t)o*D, at, j);
    if (j == 0){ float nx = x1[o] + r + cob[o]; x1[o] = nx; xb[(size_t)b*D + o] = nx; }
  }
  __syncthreads();
  { // LN3 -> xnb (global)
    float v0 = x1[t], v1 = x1[t+256];
    float mean = block_sum(v0+v1, red) * (1.f/D);
    float d0 = v0-mean, d1 = v1-mean;
    float var = block_sum(d0*d0 + d1*d1, red) * (1.f/D);
    float rs = rsqrtf(var + EPS);
    xnb[(size_t)b*D + t]       = d0*rs*g3[t]     + b3[t];
    xnb[(size_t)b*D + t + 256] = d1*rs*g3[t+256] + b3[t+256];
  }
}

__global__ __launch_bounds__(256) void k_dffn1(const float* __restrict__ xnb,
    const float* __restrict__ w1, const float* __restrict__ b1, float* __restrict__ hb){
  int blk = blockIdx.x, b = blk >> 3, ch = blk & 7, t = threadIdx.x, j = t & 7;
  __shared__ __align__(16) float xn[D];
  xn[t] = xnb[(size_t)b*D + t]; xn[t+256] = xnb[(size_t)b*D + t + 256];
  __syncthreads();
  #pragma unroll
  for (int pass = 0; pass < 8; pass++){
    int o = ch*256 + pass*32 + (t >> 3);
    float r = dot8<512>(w1 + (size_t)o*D, xn, j);
    if (j == 0) hb[(size_t)b*2048 + o] = gelu_f(r + b1[o]);
  }
}

__global__ __launch_bounds__(256) void k_dffn2(const float* __restrict__ hb,
    const float* __restrict__ w2, const float* __restrict__ b2, float* __restrict__ xb){
  int blk = blockIdx.x, b = blk >> 1, hf = blk & 1, t = threadIdx.x, j = t & 7;
  __shared__ __align__(16) float hh[2048];
  #pragma unroll
  for (int i = 0; i < 8; i++) hh[t + i*256] = hb[(size_t)b*2048 + t + i*256];
  __syncthreads();
  #pragma unroll
  for (int pass = 0; pass < 8; pass++){
    int o = hf*256 + pass*32 + (t >> 3);
    float r = dot8<2048>(w2 + (size_t)o*2048, hh, j);
    if (j == 0) xb[(size_t)b*D + o] += r + b2[o];
  }
}

// -------------------- host --------------------

extern "C" void kernel_launch(void* const* d_in, const int* in_sizes, int n_in,
                              void* d_out, int out_size, void* d_ws, size_t ws_size,
                              hipStream_t stream){
  (void)in_sizes; (void)n_in; (void)out_size; (void)ws_size;
  const float* ctx   = (const float*)d_in[0];
  const float* pos   = (const float*)d_in[1];
  const float* sa_w  = (const float*)d_in[2];
  const float* sa_b  = (const float*)d_in[3];
  const float* sa_ow = (const float*)d_in[4];
  const float* sa_ob = (const float*)d_in[5];
  const float* ca_w  = (const float*)d_in[6];
  const float* ca_b  = (const float*)d_in[7];
  const float* ca_ow = (const float*)d_in[8];
  const float* ca_ob = (const float*)d_in[9];
  const float* ln1g  = (const float*)d_in[10];
  const float* ln1b  = (const float*)d_in[11];
  const float* ln2g  = (const float*)d_in[12];
  const float* ln2b  = (const float*)d_in[13];
  const float* ln3g  = (const float*)d_in[14];
  const float* ln3b  = (const float*)d_in[15];
  const float* fw1   = (const float*)d_in[16];
  const float* fb1   = (const float*)d_in[17];
  const float* fw2   = (const float*)d_in[18];
  const float* fb2   = (const float*)d_in[19];
  const float* outw  = (const float*)d_in[20];
  const float* outb  = (const float*)d_in[21];
  float* out = (float*)d_out;

  float* w = (float*)d_ws;
  size_t off = 0;
  auto alloc = [&](size_t n){ float* p = w + off; off += n; return p; };
  float* kcache = alloc((size_t)NL*NB*SMAX*D);
  float* vcache = alloc((size_t)NL*NB*SMAX*D);
  float* ckv    = alloc((size_t)NL*NB*M*1024);
  float* X0     = alloc((size_t)NR*D);
  float* XN0    = alloc((size_t)NR*D);
  float* Q0     = alloc((size_t)NR*D);
  float* AT0    = alloc((size_t)NR*D);
  float* H0     = alloc((size_t)NR*2048);
  float* xb     = alloc((size_t)NB*D);
  float* qb     = alloc((size_t)NB*D);
  float* xnb    = alloc((size_t)NB*D);
  float* hb     = alloc((size_t)NB*2048);

  dim3 blk(256);

  // embed + one-time cross K/V for all layers (context is fixed, raw input)
  k_embed<<<NR, blk, 0, stream>>>(ctx, pos, X0);
  for (int l = 0; l < NL; l++){
    k_gemm<<<dim3(NR/64, 1024/64), blk, 0, stream>>>(
        ctx, ca_w + (size_t)l*3*D*D + (size_t)D*D, ca_b + (size_t)l*3*D + D, nullptr,
        ckv + (size_t)l*NB*M*1024, 512, 1024, 0, nullptr, nullptr, nullptr, GM_PLAIN);
  }

  // ---- prefill: 20 context positions through 6 layers, filling self K/V caches ----
  for (int l = 0; l < NL; l++){
    const float* saw = sa_w + (size_t)l*3*D*D;
    const float* sab = sa_b + (size_t)l*3*D;
    float* kcl = kcache + (size_t)l*NB*SMAX*D;
    float* vcl = vcache + (size_t)l*NB*SMAX*D;
    const float* ckl = ckv + (size_t)l*NB*M*1024;

    k_ln<<<NR, blk, 0, stream>>>(X0, XN0, ln1g + l*D, ln1b + l*D);
    k_gemm<<<dim3(NR/64, 1536/64), blk, 0, stream>>>(
        XN0, saw, sab, nullptr, nullptr, 512, D, 0, Q0, kcl, vcl, GM_QKV);
    k_sattn_pre<<<NB*H, blk, 0, stream>>>(Q0, kcl, vcl, AT0);
    k_gemm<<<dim3(NR/64, D/64), blk, 0, stream>>>(
        AT0, sa_ow + (size_t)l*D*D, sa_ob + l*D, X0, X0, 512, D, 0,
        nullptr, nullptr, nullptr, GM_PLAIN);
    k_ln<<<NR, blk, 0, stream>>>(X0, XN0, ln2g + l*D, ln2b + l*D);
    k_gemm<<<dim3(NR/64, D/64), blk, 0, stream>>>(
        XN0, ca_w + (size_t)l*3*D*D, ca_b + (size_t)l*3*D, nullptr, Q0, 512, D, 0,
        nullptr, nullptr, nullptr, GM_PLAIN);
    k_cattn_pre<<<NB*H, blk, 0, stream>>>(Q0, ckl, AT0);
    k_gemm<<<dim3(NR/64, D/64), blk, 0, stream>>>(
        AT0, ca_ow + (size_t)l*D*D, ca_ob + l*D, X0, X0, 512, D, 0,
        nullptr, nullptr, nullptr, GM_PLAIN);
    k_ln<<<NR, blk, 0, stream>>>(X0, XN0, ln3g + l*D, ln3b + l*D);
    k_gemm<<<dim3(NR/64, 2048/64), blk, 0, stream>>>(
        XN0, fw1 + (size_t)l*2048*D, fb1 + (size_t)l*2048, nullptr, H0, 512, 2048, 1,
        nullptr, nullptr, nullptr, GM_PLAIN);
    k_gemm<<<dim3(NR/64, D/64), blk, 0, stream>>>(
        H0, fw2 + (size_t)l*D*2048, fb2 + l*D, X0, X0, 2048, D, 0,
        nullptr, nullptr, nullptr, GM_PLAIN);
  }
  k_copy_last<<<NB, blk, 0, stream>>>(X0, xb);
  k_final<<<NB, blk, 0, stream>>>(xb, pos, outw, outb, out, 0, M);

  // ---- decode: 29 steps, single new position each ----
  for (int t = 1; t < T; t++){
    int p = M - 1 + t;
    for (int l = 0; l < NL; l++){
      float* kcl = kcache + (size_t)l*NB*SMAX*D;
      float* vcl = vcache + (size_t)l*NB*SMAX*D;
      const float* ckl = ckv + (size_t)l*NB*M*1024;
      k_dqkv<<<NB*6, blk, 0, stream>>>(xb, sa_w + (size_t)l*3*D*D, sa_b + (size_t)l*3*D,
          ln1g + l*D, ln1b + l*D, qb, kcl, vcl, p);
      k_dmid<<<NB, blk, 0, stream>>>(xb, qb, kcl, vcl, ckl,
          sa_ow + (size_t)l*D*D, sa_ob + l*D,
          ca_w + (size_t)l*3*D*D, ca_b + (size_t)l*3*D,
          ca_ow + (size_t)l*D*D, ca_ob + l*D,
          ln2g + l*D, ln2b + l*D, ln3g + l*D, ln3b + l*D, xnb, p);
      k_dffn1<<<NB*8, blk, 0, stream>>>(xnb, fw1 + (size_t)l*2048*D, fb1 + (size_t)l*2048, hb);
      k_dffn2<<<NB*2, blk, 0, stream>>>(hb, fw2 + (size_t)l*D*2048, fb2 + l*D, xb);
    }
    k_final<<<NB, blk, 0, stream>>>(xb, pos, outw, outb, out, t, M + t);
  }
}